// Round 4
// baseline (469.677 us; speedup 1.0000x reference)
//
#include <hip/hip_runtime.h>

#define Bb 64
#define Tt 12
#define Nn 512
#define Dd 2
#define G3 192
#define Hh 12
#define CSR_CAP 96

typedef float f32x4 __attribute__((ext_vector_type(4)));
typedef _Float16 f16;
typedef _Float16 f16x8 __attribute__((ext_vector_type(8)));
typedef unsigned int uint_t;

// XOR swizzle for 64x64 fp32 LDS tile (row stride 256B), 16B-granular.
__device__ __forceinline__ int swz4(int row, int bo) {
  return row * 256 + (bo ^ ((row & 7) << 4));
}

// ---------------------------------------------------------------------------
// init: CSR of each adjacency column; fp16 hi/lo fragment-packed weights; h0.
// g_w  (f16): [0,12288) W_ih[:, :64]^T hi ; [12288,24576) W_hh^T hi ;
//             [24576,28672) W_msg^T hi
// g_wlo(f16): [0,12288) W_ih lo ; [12288,24576) W_hh lo
// g_f (f32):  [0,384) W_ih[:,64:66] ; [384,576) b_ih ; [576,768) b_hh ;
//             [768,832) b_msg
// ---------------------------------------------------------------------------
__global__ __launch_bounds__(256) void init_kernel(
    const float* __restrict__ h0, const float* __restrict__ adj,
    const float* __restrict__ W_msg, const float* __restrict__ W_ih,
    const float* __restrict__ W_hh, const float* __restrict__ b_ih,
    const float* __restrict__ b_hh, const float* __restrict__ b_msg,
    float* __restrict__ h_ws, f16* __restrict__ g_w, f16* __restrict__ g_wlo,
    float* __restrict__ g_f, int* __restrict__ g_cj,
    float* __restrict__ g_ca, int* __restrict__ g_nnz) {
  __shared__ int s_wavecnt[4];
  const int n = blockIdx.x, tid = threadIdx.x, l = tid & 63, wt = tid >> 6;

  // CSR of column n (deterministic ballot prefix-scan)
  {
    const int j0 = tid * 2, j1 = j0 + 1;
    const float a0 = adj[j0 * Nn + n];
    const float a1 = adj[j1 * Nn + n];
    unsigned long long mk0 = __ballot(a0 > 0.f);
    unsigned long long mk1 = __ballot(a1 > 0.f);
    if (l == 0) s_wavecnt[wt] = __popcll(mk0) + __popcll(mk1);
    __syncthreads();
    int base = 0;
#pragma unroll
    for (int w = 0; w < 4; ++w)
      if (w < wt) base += s_wavecnt[w];
    unsigned long long lt = (1ull << l) - 1ull;
    int pos = base + __popcll(mk0 & lt) + __popcll(mk1 & lt);
    if (a0 > 0.f) {
      if (pos < CSR_CAP) { g_cj[n * CSR_CAP + pos] = j0; g_ca[n * CSR_CAP + pos] = a0; }
      ++pos;
    }
    if (a1 > 0.f && pos < CSR_CAP) { g_cj[n * CSR_CAP + pos] = j1; g_ca[n * CSR_CAP + pos] = a1; }
    if (tid == 0) {
      int tot = s_wavecnt[0] + s_wavecnt[1] + s_wavecnt[2] + s_wavecnt[3];
      g_nnz[n] = tot < CSR_CAP ? tot : CSR_CAP;
    }
  }

  // weight fragment packing (block 0 only)
  // frag (nt,kt): lane l elem j holds W[nt*16+(l&15)][kt*32+8*(l>>4)+j]
  if (n == 0) {
    for (int tile = wt; tile < 24; tile += 4) {
      const int nt = tile >> 1, kt = tile & 1;
      const int wrow = nt * 16 + (l & 15);
      const int kc = kt * 32 + ((l >> 4) << 3);
      const float* s2 = W_ih + wrow * 66 + kc;
      const float* s1 = W_hh + wrow * 64 + kc;
#pragma unroll
      for (int j = 0; j < 8; ++j) {
        const float w2 = s2[j];
        const f16 h2 = (f16)w2;
        g_w[tile * 512 + l * 8 + j] = h2;
        g_wlo[tile * 512 + l * 8 + j] = (f16)(w2 - (float)h2);
        const float w1 = s1[j];
        const f16 h1 = (f16)w1;
        g_w[12288 + tile * 512 + l * 8 + j] = h1;
        g_wlo[12288 + tile * 512 + l * 8 + j] = (f16)(w1 - (float)h1);
      }
    }
    for (int tile = wt; tile < 8; tile += 4) {
      const int nt = tile >> 1, kt = tile & 1;
      const int wrow = nt * 16 + (l & 15);
      const int kc = kt * 32 + ((l >> 4) << 3);
      const float* s1 = W_msg + wrow * 64 + kc;
#pragma unroll
      for (int j = 0; j < 8; ++j) g_w[24576 + tile * 512 + l * 8 + j] = (f16)s1[j];
    }
    if (tid < G3) {
      g_f[tid * 2] = W_ih[tid * 66 + 64];
      g_f[tid * 2 + 1] = W_ih[tid * 66 + 65];
      g_f[384 + tid] = b_ih[tid];
      g_f[576 + tid] = b_hh[tid];
    }
    if (tid < 64) g_f[768 + tid] = b_msg[tid];
  }

  // h0 -> h_ws (fp32 carry state)
  const float4* src = (const float4*)(h0 + ((size_t)n << 12));
  float4* dst = (float4*)(h_ws + ((size_t)n << 12));
  for (int i = tid; i < 1024; i += 256) dst[i] = src[i];
}

// ---------------------------------------------------------------------------
// hw0 = h0 @ W_msg^T + b_msg  (split-fp16 A, fp16 out; W frags from global)
// ---------------------------------------------------------------------------
__global__ __launch_bounds__(256) void hw0_kernel(
    const float* __restrict__ h0, const f16* __restrict__ g_w,
    const float* __restrict__ g_f, f16* __restrict__ hw_out) {
  __shared__ float h_lds[4096];
  const int n = blockIdx.x, tid = threadIdx.x, l = tid & 63, wt = tid >> 6;
  {
    const int row = tid >> 2, c0 = (tid & 3) << 4;
    const float4* src = (const float4*)(h0 + ((n << 6) + row) * 64 + c0);
#pragma unroll
    for (int q = 0; q < 4; ++q)
      *(float4*)((char*)h_lds + swz4(row, c0 * 4 + q * 16)) = src[q];
  }
  // own-wave rows only -> no barrier
  const int ar = wt * 16 + (l & 15);
  const int bo = (l >> 4) << 5;     // 32*(l>>4) bytes = 8 fp32 per ktile
  float4 p0 = *(const float4*)((const char*)h_lds + swz4(ar, bo));
  float4 p1 = *(const float4*)((const char*)h_lds + swz4(ar, bo + 16));
  float4 p2 = *(const float4*)((const char*)h_lds + swz4(ar, 128 + bo));
  float4 p3 = *(const float4*)((const char*)h_lds + swz4(ar, 128 + bo + 16));
  f16x8 ahi0, alo0, ahi1, alo1;
  {
    float v[16] = {p0.x, p0.y, p0.z, p0.w, p1.x, p1.y, p1.z, p1.w,
                   p2.x, p2.y, p2.z, p2.w, p3.x, p3.y, p3.z, p3.w};
#pragma unroll
    for (int j = 0; j < 8; ++j) {
      f16 h = (f16)v[j];          ahi0[j] = h; alo0[j] = (f16)(v[j] - (float)h);
      f16 g = (f16)v[8 + j];      ahi1[j] = g; alo1[j] = (f16)(v[8 + j] - (float)g);
    }
  }
#pragma unroll
  for (int nt = 0; nt < 4; ++nt) {
    const f16x8 b0 = *(const f16x8*)(g_w + 24576 + (nt * 2 + 0) * 512 + l * 8);
    const f16x8 b1 = *(const f16x8*)(g_w + 24576 + (nt * 2 + 1) * 512 + l * 8);
    f32x4 c = {0.f, 0.f, 0.f, 0.f};
    c = __builtin_amdgcn_mfma_f32_16x16x32_f16(ahi0, b0, c, 0, 0, 0);
    c = __builtin_amdgcn_mfma_f32_16x16x32_f16(alo0, b0, c, 0, 0, 0);
    c = __builtin_amdgcn_mfma_f32_16x16x32_f16(ahi1, b1, c, 0, 0, 0);
    c = __builtin_amdgcn_mfma_f32_16x16x32_f16(alo1, b1, c, 0, 0, 0);
    const int col = nt * 16 + (l & 15);
    const float bm = g_f[768 + col];
#pragma unroll
    for (int g = 0; g < 4; ++g) {
      const int row = wt * 16 + ((l >> 4) << 2) + g;
      hw_out[((n << 6) + row) * 64 + col] = (f16)(c[g] + bm);
    }
  }
}

// ---------------------------------------------------------------------------
// one GRU message-passing step (block = node n)
// ---------------------------------------------------------------------------
__global__ __launch_bounds__(256, 2) void step_kernel(
    const float* __restrict__ xin, float* __restrict__ h_ws,
    const uint4* __restrict__ g_blob, const f16* __restrict__ g_wlo,
    const int* __restrict__ g_cj, const float* __restrict__ g_ca,
    const int* __restrict__ g_nnz, const f16* __restrict__ hw_rd,
    f16* __restrict__ hw_wr, int t) {
  __shared__ uint4 sBlob[3792];   // 57344B f16 hi-frags + 3328B fp32 extras
  __shared__ float h_lds[4096];   // h fp32, swizzled
  __shared__ int s_cj[CSR_CAP];
  __shared__ float s_ca[CSR_CAP];
  const f16* sBih = (const f16*)sBlob;
  const f16* sBhh = sBih + 12288;
  const f16* sBmsg = sBih + 24576;
  const float* sF = (const float*)(sBih + 28672);
  const float* sWx = sF;          // [384]
  const float* s_bih = sF + 384;
  const float* s_bhh = sF + 576;
  const float* s_bmsg = sF + 768;

  const int n = blockIdx.x, tid = threadIdx.x, l = tid & 63, wt = tid >> 6;

  for (int i = tid; i < 3792; i += 256) sBlob[i] = g_blob[i];
  if (tid < CSR_CAP) {
    s_cj[tid] = g_cj[n * CSR_CAP + tid];
    s_ca[tid] = g_ca[n * CSR_CAP + tid];
  }
  const int nnz = g_nnz[n];

  // h(t) -> h_lds fp32 (wave-aligned rows)
  {
    const int row = tid >> 2, c0 = (tid & 3) << 4;
    const float4* src = (const float4*)(h_ws + ((n << 6) + row) * 64 + c0);
#pragma unroll
    for (int q = 0; q < 4; ++q)
      *(float4*)((char*)h_lds + swz4(row, c0 * 4 + q * 16)) = src[q];
  }
  // fp32 carry in MFMA C layout
  float hreg[4][4];
#pragma unroll
  for (int ct = 0; ct < 4; ++ct)
#pragma unroll
    for (int g = 0; g < 4; ++g) {
      const int row = wt * 16 + ((l >> 4) << 2) + g;
      hreg[ct][g] = h_ws[((n << 6) + row) * 64 + ct * 16 + (l & 15)];
    }
  __syncthreads();   // sBlob + s_cj cross-wave

  // m gathered DIRECTLY in A-fragment layout (registers, fp32):
  // lane owns m[b = 16wt+(l&15)][8*(l>>4)+j (+32kt)]
  const int mb = wt * 16 + (l & 15);
  const int mc0 = (l >> 4) << 3;
  float accm[16];
#pragma unroll
  for (int e = 0; e < 16; ++e) accm[e] = 0.f;
  for (int k = 0; k < nnz; ++k) {
    const int j = s_cj[k];
    const float a = s_ca[k];
    const f16* base = hw_rd + ((j << 6) + mb) * 64 + mc0;
    const f16x8 v0 = *(const f16x8*)(base);
    const f16x8 v1 = *(const f16x8*)(base + 32);
#pragma unroll
    for (int jj = 0; jj < 8; ++jj) {
      accm[jj] += a * (float)v0[jj];
      accm[8 + jj] += a * (float)v1[jj];
    }
  }
  f16x8 mhi0, mlo0, mhi1, mlo1;
#pragma unroll
  for (int jj = 0; jj < 8; ++jj) {
    f16 h = (f16)accm[jj];       mhi0[jj] = h; mlo0[jj] = (f16)(accm[jj] - (float)h);
    f16 g = (f16)accm[8 + jj];   mhi1[jj] = g; mlo1[jj] = (f16)(accm[8 + jj] - (float)g);
  }

  // h(t) A-frags hi/lo from h_lds
  const int ar = wt * 16 + (l & 15);
  const int bo = (l >> 4) << 5;
  f16x8 ahi0, alo0, ahi1, alo1;
  {
    float4 p0 = *(const float4*)((const char*)h_lds + swz4(ar, bo));
    float4 p1 = *(const float4*)((const char*)h_lds + swz4(ar, bo + 16));
    float4 p2 = *(const float4*)((const char*)h_lds + swz4(ar, 128 + bo));
    float4 p3 = *(const float4*)((const char*)h_lds + swz4(ar, 128 + bo + 16));
    float v[16] = {p0.x, p0.y, p0.z, p0.w, p1.x, p1.y, p1.z, p1.w,
                   p2.x, p2.y, p2.z, p2.w, p3.x, p3.y, p3.z, p3.w};
#pragma unroll
    for (int j = 0; j < 8; ++j) {
      f16 h = (f16)v[j];        ahi0[j] = h; alo0[j] = (f16)(v[j] - (float)h);
      f16 g = (f16)v[8 + j];    ahi1[j] = g; alo1[j] = (f16)(v[8 + j] - (float)g);
    }
  }

  // gi = m @ W_ih^T ; gh = h @ W_hh^T  (split-fp16: hi*Whi + lo*Whi + hi*Wlo)
  f32x4 cgi[12], cgh[12];
#pragma unroll
  for (int nt = 0; nt < 12; ++nt) {
    cgi[nt] = {0.f, 0.f, 0.f, 0.f};
    cgh[nt] = {0.f, 0.f, 0.f, 0.f};
  }
#pragma unroll
  for (int nt = 0; nt < 12; ++nt) {
    const f16x8 bh0 = *(const f16x8*)(sBhh + (nt * 2 + 0) * 512 + l * 8);
    const f16x8 bh1 = *(const f16x8*)(sBhh + (nt * 2 + 1) * 512 + l * 8);
    const f16x8 bhL0 = *(const f16x8*)(g_wlo + 12288 + (nt * 2 + 0) * 512 + l * 8);
    const f16x8 bhL1 = *(const f16x8*)(g_wlo + 12288 + (nt * 2 + 1) * 512 + l * 8);
    cgh[nt] = __builtin_amdgcn_mfma_f32_16x16x32_f16(ahi0, bh0, cgh[nt], 0, 0, 0);
    cgh[nt] = __builtin_amdgcn_mfma_f32_16x16x32_f16(alo0, bh0, cgh[nt], 0, 0, 0);
    cgh[nt] = __builtin_amdgcn_mfma_f32_16x16x32_f16(ahi1, bh1, cgh[nt], 0, 0, 0);
    cgh[nt] = __builtin_amdgcn_mfma_f32_16x16x32_f16(alo1, bh1, cgh[nt], 0, 0, 0);
    cgh[nt] = __builtin_amdgcn_mfma_f32_16x16x32_f16(ahi0, bhL0, cgh[nt], 0, 0, 0);
    cgh[nt] = __builtin_amdgcn_mfma_f32_16x16x32_f16(ahi1, bhL1, cgh[nt], 0, 0, 0);
    const f16x8 bi0 = *(const f16x8*)(sBih + (nt * 2 + 0) * 512 + l * 8);
    const f16x8 bi1 = *(const f16x8*)(sBih + (nt * 2 + 1) * 512 + l * 8);
    const f16x8 biL0 = *(const f16x8*)(g_wlo + (nt * 2 + 0) * 512 + l * 8);
    const f16x8 biL1 = *(const f16x8*)(g_wlo + (nt * 2 + 1) * 512 + l * 8);
    cgi[nt] = __builtin_amdgcn_mfma_f32_16x16x32_f16(mhi0, bi0, cgi[nt], 0, 0, 0);
    cgi[nt] = __builtin_amdgcn_mfma_f32_16x16x32_f16(mlo0, bi0, cgi[nt], 0, 0, 0);
    cgi[nt] = __builtin_amdgcn_mfma_f32_16x16x32_f16(mhi1, bi1, cgi[nt], 0, 0, 0);
    cgi[nt] = __builtin_amdgcn_mfma_f32_16x16x32_f16(mlo1, bi1, cgi[nt], 0, 0, 0);
    cgi[nt] = __builtin_amdgcn_mfma_f32_16x16x32_f16(mhi0, biL0, cgi[nt], 0, 0, 0);
    cgi[nt] = __builtin_amdgcn_mfma_f32_16x16x32_f16(mhi1, biL1, cgi[nt], 0, 0, 0);
  }

  // GRU gates (fp32): update carry, h_ws, h_lds (fp32, own-wave rows)
  float x0[4], x1[4];
#pragma unroll
  for (int g = 0; g < 4; ++g) {
    const int brow = wt * 16 + ((l >> 4) << 2) + g;
    const float* xp = xin + ((brow * Tt + t) * Nn + n) * Dd;
    x0[g] = xp[0];
    x1[g] = xp[1];
  }
#pragma unroll
  for (int ct = 0; ct < 4; ++ct) {
    const int colr = ct * 16 + (l & 15);
    const float wr0 = sWx[colr * 2], wr1 = sWx[colr * 2 + 1];
    const float wz0 = sWx[(colr + 64) * 2], wz1 = sWx[(colr + 64) * 2 + 1];
    const float wn0 = sWx[(colr + 128) * 2], wn1 = sWx[(colr + 128) * 2 + 1];
    const float bir = s_bih[colr], biz = s_bih[colr + 64], bin_ = s_bih[colr + 128];
    const float bhr = s_bhh[colr], bhz = s_bhh[colr + 64], bhn = s_bhh[colr + 128];
#pragma unroll
    for (int g = 0; g < 4; ++g) {
      const int row = wt * 16 + ((l >> 4) << 2) + g;
      const float gir = cgi[ct][g] + x0[g] * wr0 + x1[g] * wr1 + bir;
      const float giz = cgi[ct + 4][g] + x0[g] * wz0 + x1[g] * wz1 + biz;
      const float gin = cgi[ct + 8][g] + x0[g] * wn0 + x1[g] * wn1 + bin_;
      const float ghr = cgh[ct][g] + bhr;
      const float ghz = cgh[ct + 4][g] + bhz;
      const float ghn = cgh[ct + 8][g] + bhn;
      const float rg = 1.f / (1.f + __expf(-(gir + ghr)));
      const float zg = 1.f / (1.f + __expf(-(giz + ghz)));
      const float pa = gin + rg * ghn;
      const float e2 = __expf(-2.f * fabsf(pa));
      float th = (1.f - e2) / (1.f + e2);
      th = copysignf(th, pa);
      const float hn = (1.f - zg) * th + zg * hreg[ct][g];
      h_ws[((n << 6) + row) * 64 + colr] = hn;
      *(float*)((char*)h_lds + swz4(row, colr * 4)) = hn;
    }
  }

  // hw(t+1) = h(t+1) @ W_msg^T + b_msg  (own-wave rows; direct fp16 store)
  if (t < Tt - 1) {
    f16x8 nhi0, nlo0, nhi1, nlo1;
    {
      float4 p0 = *(const float4*)((const char*)h_lds + swz4(ar, bo));
      float4 p1 = *(const float4*)((const char*)h_lds + swz4(ar, bo + 16));
      float4 p2 = *(const float4*)((const char*)h_lds + swz4(ar, 128 + bo));
      float4 p3 = *(const float4*)((const char*)h_lds + swz4(ar, 128 + bo + 16));
      float v[16] = {p0.x, p0.y, p0.z, p0.w, p1.x, p1.y, p1.z, p1.w,
                     p2.x, p2.y, p2.z, p2.w, p3.x, p3.y, p3.z, p3.w};
#pragma unroll
      for (int j = 0; j < 8; ++j) {
        f16 h = (f16)v[j];        nhi0[j] = h; nlo0[j] = (f16)(v[j] - (float)h);
        f16 g = (f16)v[8 + j];    nhi1[j] = g; nlo1[j] = (f16)(v[8 + j] - (float)g);
      }
    }
#pragma unroll
    for (int nt = 0; nt < 4; ++nt) {
      const f16x8 b0 = *(const f16x8*)(sBmsg + (nt * 2 + 0) * 512 + l * 8);
      const f16x8 b1 = *(const f16x8*)(sBmsg + (nt * 2 + 1) * 512 + l * 8);
      f32x4 c = {0.f, 0.f, 0.f, 0.f};
      c = __builtin_amdgcn_mfma_f32_16x16x32_f16(nhi0, b0, c, 0, 0, 0);
      c = __builtin_amdgcn_mfma_f32_16x16x32_f16(nlo0, b0, c, 0, 0, 0);
      c = __builtin_amdgcn_mfma_f32_16x16x32_f16(nhi1, b1, c, 0, 0, 0);
      c = __builtin_amdgcn_mfma_f32_16x16x32_f16(nlo1, b1, c, 0, 0, 0);
      const int col = nt * 16 + (l & 15);
      const float bm = s_bmsg[col];
#pragma unroll
      for (int g = 0; g < 4; ++g) {
        const int row = wt * 16 + ((l >> 4) << 2) + g;
        hw_wr[((n << 6) + row) * 64 + col] = (f16)(c[g] + bm);
      }
    }
  }
}

// ---------------------------------------------------------------------------
// out[b,hz,n,0] = h[n,b,:] . W_out[hz,:] + b_out[hz]
// ---------------------------------------------------------------------------
__global__ __launch_bounds__(256) void out_kernel(
    const float* __restrict__ h_ws, const float* __restrict__ W_out,
    const float* __restrict__ b_out, float* __restrict__ out) {
  __shared__ float sWo[Hh * 64];
  __shared__ float sbo[Hh];
  const int n = blockIdx.x, tid = threadIdx.x;
  for (int i = tid; i < Hh * 64; i += 256) sWo[i] = W_out[i];
  if (tid < Hh) sbo[tid] = b_out[tid];
  __syncthreads();
  for (int q = tid; q < Bb * Hh; q += 256) {
    const int b = q / Hh;
    const int o = q - b * Hh;
    const float* hr = h_ws + ((n << 6) + b) * 64;
    const float* wr = sWo + o * 64;
    float acc = sbo[o];
#pragma unroll 8
    for (int k = 0; k < 64; ++k) acc += hr[k] * wr[k];
    out[(b * Hh + o) * Nn + n] = acc;
  }
}

extern "C" void kernel_launch(void* const* d_in, const int* in_sizes, int n_in,
                              void* d_out, int out_size, void* d_ws, size_t ws_size,
                              hipStream_t stream) {
  const float* xin = (const float*)d_in[0];
  const float* h0 = (const float*)d_in[1];
  const float* adj = (const float*)d_in[2];
  const float* W_msg = (const float*)d_in[3];
  const float* b_msg = (const float*)d_in[4];
  const float* W_ih = (const float*)d_in[5];
  const float* W_hh = (const float*)d_in[6];
  const float* b_ih = (const float*)d_in[7];
  const float* b_hh = (const float*)d_in[8];
  const float* W_out = (const float*)d_in[9];
  const float* b_out = (const float*)d_in[10];
  float* out = (float*)d_out;

  // ws: [0,8M) h fp32 | [8M,12M) hwA f16 | [12M,16M) hwB f16 |
  //     16M: g_w hi (57344B) + g_f (3328B) | 16M+61440: g_wlo (49152B) |
  //     16M+110592: g_cj | +196608: g_ca | +196608: g_nnz
  char* ws = (char*)d_ws;
  float* h_ws = (float*)ws;
  f16* hwA = (f16*)(ws + (8u << 20));
  f16* hwB = (f16*)(ws + (12u << 20));
  char* base16 = ws + (16u << 20);
  f16* g_w = (f16*)base16;
  float* g_f = (float*)(base16 + 57344);
  f16* g_wlo = (f16*)(base16 + 61440);
  int* g_cj = (int*)(base16 + 110592);
  float* g_ca = (float*)(base16 + 110592 + 196608);
  int* g_nnz = (int*)(base16 + 110592 + 393216);
  const uint4* g_blob = (const uint4*)g_w;

  init_kernel<<<Nn, 256, 0, stream>>>(h0, adj, W_msg, W_ih, W_hh, b_ih, b_hh,
                                      b_msg, h_ws, g_w, g_wlo, g_f, g_cj, g_ca,
                                      g_nnz);
  hw0_kernel<<<Nn, 256, 0, stream>>>(h0, g_w, g_f, hwA);
  for (int t = 0; t < Tt; ++t) {
    f16* rd = (t & 1) ? hwB : hwA;
    f16* wr = (t & 1) ? hwA : hwB;
    step_kernel<<<Nn, 256, 0, stream>>>(xin, h_ws, g_blob, g_wlo, g_cj, g_ca,
                                        g_nnz, rd, wr, t);
  }
  out_kernel<<<Nn, 256, 0, stream>>>(h_ws, W_out, b_out, out);
}